// Round 6
// baseline (329.518 us; speedup 1.0000x reference)
//
#include <hip/hip_runtime.h>

// Problem constants: x:(B,T,2P) f32, resolution:(B,T,2) f32, origin:(B,T,2) f32
// -> out:(B,T,H,W,P) f32 one-hot raster grid (320 MB, 99.99% zeros).
#define BB 32
#define TT 10
#define PP 25
#define HH 100
#define WW 100

#define CELLS_PER_BT (HH * WW)      // 10,000 cells per (b,t)
// Work units of 100 floats (= 4 cells = 25 float4): cells never straddle units.
// Total: 32*10*100*100*25 floats / 100 = 800,000 units.
#define TOTAL_UNITS 800000
#define NBLOCKS 2048                // exactly machine residency: 256 CU x 8 blocks
#define UNITS_BASE 390              // 2048*390 = 798,720
#define UNITS_EXTRA 1280            // first 1280 blocks take +1 unit (798,720+1,280 = 800,000)

typedef float f32x4 __attribute__((ext_vector_type(4)));

// R5 lesson: 3200 blocks vs 2048-block residency => 2 rounds for some wave
// slots, 1 for others => 78% store efficiency. This version uses EXACTLY 2048
// blocks (all resident simultaneously, one block per wave-slot, ~156 KB
// contiguous chunk each) so the zero phase is a perfectly balanced memset.
// Fixup after __syncthreads (vmcnt(0) drain) writes the <=25 one-cells per bt
// that land in this block's own chunk; a chunk spans at most 2 bt's.
__global__ __launch_bounds__(256, 8) void raster_zero_fixup_kernel(
        const float* __restrict__ x,
        const float* __restrict__ resolution,
        const float* __restrict__ origin,
        float* __restrict__ out) {
    const int b   = blockIdx.x;    // 0..2047
    const int tid = threadIdx.x;

    const int start = b * UNITS_BASE + (b < UNITS_EXTRA ? b : UNITS_EXTRA);
    const int count = UNITS_BASE + (b < UNITS_EXTRA ? 1 : 0);   // 390 or 391 units

    // ---- Phase 1: pure memset of this block's chunk (count*100 floats).
    f32x4* const chunk = reinterpret_cast<f32x4*>(out) + (size_t)start * 25;
    const int nf4 = count * 25;    // 9750 or 9775 float4
    const f32x4 z = {0.0f, 0.0f, 0.0f, 0.0f};
#pragma unroll 4
    for (int i = tid; i < nf4; i += 256) {
        chunk[i] = z;
    }

    __syncthreads();  // vmcnt(0) drain: zeros retired before fixup stores

    // ---- Phase 2: fixup one-cells inside this chunk's global cell range.
    // Chunk covers global cells [c0, c0+nc), nc ~ 1564 < 10,000 => at most
    // 2 distinct bt's overlap.
    const int c0  = start * 4;
    const int nc  = count * 4;
    const int bt0 = c0 / CELLS_PER_BT;
    const int bt1 = (c0 + nc - 1) / CELLS_PER_BT;

    int bt = -1, p = 0;
    if (tid < PP) {
        bt = bt0; p = tid;
    } else if (tid >= 32 && tid < 32 + PP && bt1 != bt0) {
        bt = bt1; p = tid - 32;
    }
    if (bt >= 0) {
        const float px = x[bt * (2 * PP) + 2 * p];        // x-coord
        const float py = x[bt * (2 * PP) + 2 * p + 1];    // y-coord
        const float r0 = resolution[bt * 2 + 0];          // row uses res[...,0]
        const float r1 = resolution[bt * 2 + 1];          // col uses res[...,1]
        const float o0 = origin[bt * 2 + 0];
        const float o1 = origin[bt * 2 + 1];
        // jnp .astype(int32) truncates toward zero, same as C cast.
        const int row = (int)(py / r0 + o0);
        const int col = (int)(px / r1 + o1);
        if (row >= 0 && row < HH && col >= 0 && col < WW) {
            const int gcell = bt * CELLS_PER_BT + row * WW + col;
            if (gcell >= c0 && gcell < c0 + nc) {
                out[(size_t)gcell * PP + p] = 1.0f;
            }
        }
    }
}

extern "C" void kernel_launch(void* const* d_in, const int* in_sizes, int n_in,
                              void* d_out, int out_size, void* d_ws, size_t ws_size,
                              hipStream_t stream) {
    const float* x          = (const float*)d_in[0];
    const float* resolution = (const float*)d_in[1];
    const float* origin     = (const float*)d_in[2];
    float* out = (float*)d_out;

    // Single dispatch, perfectly balanced: every logical output element is
    // written exactly once as zero, then <=8000 elements overwritten with 1.0
    // by the owning block after its barrier.
    raster_zero_fixup_kernel<<<NBLOCKS, 256, 0, stream>>>(x, resolution, origin,
                                                          out);
}

// Round 7
// 311.806 us; speedup vs baseline: 1.0568x; 1.0568x over previous
//
#include <hip/hip_runtime.h>

// Problem constants (from reference): x:(B,T,2P) f32, resolution:(B,T,2) f32,
// origin:(B,T,2) f32 -> out:(B,T,H,W,P) f32 one-hot raster grid.
//
// FINAL STRUCTURE (verified best across 7 rounds): hipMemsetAsync (rocclr's
// tuned fill, ~51 us for 320 MB @ ~6.3 TB/s) + tiny 8000-thread scatter
// (~5 us). All fused single-dispatch variants (dense compare-write, zero+
// fixup with 3200/2048 balanced blocks) measured 317-343 us vs 312 us for
// this — rocclr's fill is at the achievable HBM write ceiling and a custom
// zero-phase never matched it. Remaining time is harness-fixed: 1.28 GB
// poison fill (~204 us) + launch/reset overhead (~50 us).
#define BB 32
#define TT 10
#define PP 25
#define HH 100
#define WW 100

__global__ void raster_scatter_kernel(const float* __restrict__ x,
                                      const float* __restrict__ resolution,
                                      const float* __restrict__ origin,
                                      float* __restrict__ out) {
    int tid = blockIdx.x * blockDim.x + threadIdx.x;
    const int N = BB * TT * PP;  // 8000
    if (tid >= N) return;

    int p  = tid % PP;
    int bt = tid / PP;           // fused (b,t) index, 0..319

    // points layout: x[bt][2p] = x-coord, x[bt][2p+1] = y-coord
    const float px = x[bt * (2 * PP) + 2 * p];
    const float py = x[bt * (2 * PP) + 2 * p + 1];
    const float r0 = resolution[bt * 2 + 0];  // row uses res[...,0]
    const float r1 = resolution[bt * 2 + 1];  // col uses res[...,1]
    const float o0 = origin[bt * 2 + 0];
    const float o1 = origin[bt * 2 + 1];

    // jnp .astype(int32) truncates toward zero, same as C cast.
    int row = (int)(py / r0 + o0);
    int col = (int)(px / r1 + o1);

    if (row >= 0 && row < HH && col >= 0 && col < WW) {
        size_t idx = (((size_t)bt * HH + (size_t)row) * WW + (size_t)col) * PP + (size_t)p;
        out[idx] = 1.0f;
    }
}

extern "C" void kernel_launch(void* const* d_in, const int* in_sizes, int n_in,
                              void* d_out, int out_size, void* d_ws, size_t ws_size,
                              hipStream_t stream) {
    const float* x          = (const float*)d_in[0];
    const float* resolution = (const float*)d_in[1];
    const float* origin     = (const float*)d_in[2];
    float* out = (float*)d_out;

    // Zero exactly the logical output region (320,000,000 bytes). This is the
    // same byte count under either interpretation of out_size (elements or
    // bytes verified equivalent in R0/R1: both gave identical dur).
    const size_t out_bytes = (size_t)BB * TT * HH * WW * PP * sizeof(float);
    hipMemsetAsync(out, 0, out_bytes, stream);

    const int N = BB * TT * PP;  // 8000 points
    raster_scatter_kernel<<<(N + 255) / 256, 256, 0, stream>>>(x, resolution, origin, out);
}